// Round 7
// baseline (264.277 us; speedup 1.0000x reference)
//
#include <hip/hip_runtime.h>

typedef __bf16 bf16;
typedef __bf16 bf16x2 __attribute__((ext_vector_type(2)));
typedef __bf16 bf16x4 __attribute__((ext_vector_type(4)));
typedef __bf16 bf16x8 __attribute__((ext_vector_type(8)));
typedef float f32x4 __attribute__((ext_vector_type(4)));

typedef __attribute__((address_space(1))) const void g_void;
typedef __attribute__((address_space(3))) void l_void;

constexpr int Bsz = 4, S = 2048, H = 512, NH = 8, DH = 64;
constexpr int M = Bsz * S;   // 8192 rows
constexpr int K = H;         // 512 reduction dim
constexpr int WELEM = H * H; // 262144 elems per weight matrix
constexpr float LOG2E  = 1.44269504f;
constexpr float QSCALE = 0.125f * LOG2E;  // fold 1/sqrt(DH)*log2e into q

#if __has_builtin(__builtin_amdgcn_exp2f)
#define EXP2(x) __builtin_amdgcn_exp2f(x)
#else
#define EXP2(x) exp2f(x)
#endif

// ---------------------------------------------------------------------------
// Weight convert: fp32 -> bf16. grid=(256,4): y picks which weight.
// ---------------------------------------------------------------------------
__global__ __launch_bounds__(256) void convert_w(
    const float* __restrict__ w0, const float* __restrict__ w1,
    const float* __restrict__ w2, const float* __restrict__ w3,
    bf16* __restrict__ dst) {
    int y = blockIdx.y;
    const float* src = (y == 0) ? w0 : (y == 1) ? w1 : (y == 2) ? w2 : w3;
    bf16* d = dst + (size_t)y * WELEM;
    int i = (blockIdx.x * 256 + threadIdx.x) * 4;
    float4 v = *(const float4*)(src + i);
    bf16x4 o;
    o.x = (bf16)v.x; o.y = (bf16)v.y; o.z = (bf16)v.z; o.w = (bf16)v.w;
    *(bf16x4*)(d + i) = o;
}

// ---------------------------------------------------------------------------
// LayerNorm, one row per WAVE (no LDS, no barrier). grid = M/4, block 256.
// ---------------------------------------------------------------------------
__global__ __launch_bounds__(256) void ln_f32_bf16(
    const float* __restrict__ x, const float* __restrict__ g,
    const float* __restrict__ b, bf16* __restrict__ y) {
    int w = threadIdx.x >> 6, lane = threadIdx.x & 63;
    int row = blockIdx.x * 4 + w;
    const float* xr = x + (size_t)row * H + lane * 8;
    float4 a = *(const float4*)xr;
    float4 c = *(const float4*)(xr + 4);
    float s  = (a.x + a.y) + (a.z + a.w) + (c.x + c.y) + (c.z + c.w);
    float s2 = a.x*a.x + a.y*a.y + a.z*a.z + a.w*a.w
             + c.x*c.x + c.y*c.y + c.z*c.z + c.w*c.w;
    for (int off = 1; off < 64; off <<= 1) {
        s  += __shfl_xor(s,  off, 64);
        s2 += __shfl_xor(s2, off, 64);
    }
    float mu  = s * (1.0f / H);
    float var = s2 * (1.0f / H) - mu * mu;
    float inv = rsqrtf(var + 1e-12f);
    float4 g0 = *(const float4*)(g + lane * 8);
    float4 g1 = *(const float4*)(g + lane * 8 + 4);
    float4 b0 = *(const float4*)(b + lane * 8);
    float4 b1 = *(const float4*)(b + lane * 8 + 4);
    bf16x8 o;
    o[0] = (bf16)((a.x - mu) * inv * g0.x + b0.x);
    o[1] = (bf16)((a.y - mu) * inv * g0.y + b0.y);
    o[2] = (bf16)((a.z - mu) * inv * g0.z + b0.z);
    o[3] = (bf16)((a.w - mu) * inv * g0.w + b0.w);
    o[4] = (bf16)((c.x - mu) * inv * g1.x + b1.x);
    o[5] = (bf16)((c.y - mu) * inv * g1.y + b1.y);
    o[6] = (bf16)((c.z - mu) * inv * g1.z + b1.z);
    o[7] = (bf16)((c.w - mu) * inv * g1.w + b1.w);
    *(bf16x8*)(y + (size_t)row * H + lane * 8) = o;
}

__global__ __launch_bounds__(256) void ln_bf16_f32(
    const bf16* __restrict__ x, const float* __restrict__ g,
    const float* __restrict__ b, float* __restrict__ y) {
    int w = threadIdx.x >> 6, lane = threadIdx.x & 63;
    int row = blockIdx.x * 4 + w;
    bf16x8 xv = *(const bf16x8*)(x + (size_t)row * H + lane * 8);
    float v[8];
    float s = 0.0f, s2 = 0.0f;
    #pragma unroll
    for (int r = 0; r < 8; r++) {
        v[r] = (float)xv[r];
        s += v[r]; s2 += v[r] * v[r];
    }
    for (int off = 1; off < 64; off <<= 1) {
        s  += __shfl_xor(s,  off, 64);
        s2 += __shfl_xor(s2, off, 64);
    }
    float mu  = s * (1.0f / H);
    float var = s2 * (1.0f / H) - mu * mu;
    float inv = rsqrtf(var + 1e-12f);
    float4 g0 = *(const float4*)(g + lane * 8);
    float4 g1 = *(const float4*)(g + lane * 8 + 4);
    float4 b0 = *(const float4*)(b + lane * 8);
    float4 b1 = *(const float4*)(b + lane * 8 + 4);
    float4 o0, o1;
    o0.x = (v[0] - mu) * inv * g0.x + b0.x;
    o0.y = (v[1] - mu) * inv * g0.y + b0.y;
    o0.z = (v[2] - mu) * inv * g0.z + b0.z;
    o0.w = (v[3] - mu) * inv * g0.w + b0.w;
    o1.x = (v[4] - mu) * inv * g1.x + b1.x;
    o1.y = (v[5] - mu) * inv * g1.y + b1.y;
    o1.z = (v[6] - mu) * inv * g1.z + b1.z;
    o1.w = (v[7] - mu) * inv * g1.w + b1.w;
    *(float4*)(y + (size_t)row * H + lane * 8) = o0;
    *(float4*)(y + (size_t)row * H + lane * 8 + 4) = o1;
}

// ---------------------------------------------------------------------------
// m97-style GEMM mainloop: C[128x128] tile of A[M,K]@W[N,K]^T (unchanged R6).
// ---------------------------------------------------------------------------
__device__ inline void gemm128_mainloop(const bf16* __restrict__ A,
                                        const bf16* __restrict__ W,
                                        int bm, int bn,
                                        bf16* As, bf16* Bs, f32x4 acc[4][4]) {
    int t = threadIdx.x;
    int lane = t & 63, wid = t >> 6;
    int quad = lane >> 4, n = lane & 15;
    int wm = wid & 1, wn = wid >> 1;
    int sw = (n & 7) * 8;
    int srow = lane >> 3;
    int scol = (lane & 7) * 8;
    for (int kt = 0; kt < K; kt += 64) {
        __syncthreads();
        #pragma unroll
        for (int i = 0; i < 4; i++) {
            int chunk = wid * 4 + i;
            int row = chunk * 8 + srow;
            int csrc = scol ^ ((row & 7) * 8);
            __builtin_amdgcn_global_load_lds(
                (g_void*)&A[(size_t)(bm + row) * K + kt + csrc],
                (l_void*)&As[chunk * 512], 16, 0, 0);
            __builtin_amdgcn_global_load_lds(
                (g_void*)&W[(size_t)(bn + row) * K + kt + csrc],
                (l_void*)&Bs[chunk * 512], 16, 0, 0);
        }
        __syncthreads();
        #pragma unroll
        for (int half = 0; half < 2; half++) {
            bf16x8 af[4], bf[4];
            #pragma unroll
            for (int mi = 0; mi < 4; mi++) {
                int c = (half * 32 + quad * 8) ^ sw;
                af[mi] = *(const bf16x8*)&As[(wm * 64 + mi * 16 + n) * 64 + c];
                bf[mi] = *(const bf16x8*)&Bs[(wn * 64 + mi * 16 + n) * 64 + c];
            }
            #pragma unroll
            for (int mi = 0; mi < 4; mi++)
                #pragma unroll
                for (int ni = 0; ni < 4; ni++)
                    acc[mi][ni] = __builtin_amdgcn_mfma_f32_16x16x32_bf16(
                        af[mi], bf[ni], acc[mi][ni], 0, 0, 0);
        }
    }
}

// QKV projection. grid = (M/128, H/128, 3). z=0:q*QSCALE, z=1:k, z=2: v
// stored [B,NH,DH,S] via LDS transpose (coalesced 128B stores, not scatter).
constexpr int LDTT = 136;   // transpose tile row stride (128+8, mult of 8)

__global__ __launch_bounds__(256) void gemm_qkv(
    const bf16* __restrict__ h, const bf16* __restrict__ wb,
    const float* __restrict__ bq, const float* __restrict__ bk,
    const float* __restrict__ bv,
    bf16* __restrict__ qd, bf16* __restrict__ kd, bf16* __restrict__ vtd) {
    __shared__ alignas(16) bf16 sm[128 * LDTT];   // union: staging / transpose
    bf16* As = sm;
    bf16* Bs = sm + 8192;
    int bm = blockIdx.x * 128, bn = blockIdx.y * 128, z = blockIdx.z;
    const bf16* W = wb + (size_t)z * WELEM;
    const float* bias = (z == 0) ? bq : (z == 1) ? bk : bv;
    f32x4 acc[4][4];
    for (int mi = 0; mi < 4; mi++)
        for (int ni = 0; ni < 4; ni++)
            for (int r = 0; r < 4; r++) acc[mi][ni][r] = 0.0f;
    gemm128_mainloop(h, W, bm, bn, As, Bs, acc);
    int t = threadIdx.x;
    int lane = t & 63, wid = t >> 6;
    int quad = lane >> 4, n = lane & 15;
    int wm = wid & 1, wn = wid >> 1;
    if (z < 2) {
        bf16* dst = (z == 0) ? qd : kd;
        for (int mi = 0; mi < 4; mi++)
            for (int ni = 0; ni < 4; ni++)
                for (int r = 0; r < 4; r++) {
                    int i = bm + wm * 64 + mi * 16 + quad * 4 + r;
                    int j = bn + wn * 64 + ni * 16 + n;
                    float val = acc[mi][ni][r] + bias[j];
                    if (z == 0) val *= QSCALE;
                    int b = i >> 11, srow = i & (S - 1);
                    int nh = j >> 6, d = j & (DH - 1);
                    dst[(((size_t)(b * NH + nh)) * S + srow) * DH + d] = (bf16)val;
                }
    } else {
        __syncthreads();                 // mainloop LDS reads done
        #pragma unroll
        for (int mi = 0; mi < 4; mi++)
            #pragma unroll
            for (int ni = 0; ni < 4; ni++) {
                int j = wn * 64 + ni * 16 + n;
                float bj = bias[bn + j];
                bf16x4 pk;
                for (int r = 0; r < 4; r++) pk[r] = (bf16)(acc[mi][ni][r] + bj);
                *(bf16x4*)&sm[j * LDTT + wm * 64 + mi * 16 + quad * 4] = pk;
            }
        __syncthreads();
        int jr = t >> 1, ih = (t & 1) * 64;
        int jg = bn + jr;
        int nh2 = jg >> 6, d2 = jg & (DH - 1);
        int b2 = bm >> 11, sr = bm & (S - 1);
        bf16* dstp = &vtd[(((size_t)(b2 * NH + nh2)) * DH + d2) * S + sr + ih];
        const bf16* srcp = &sm[jr * LDTT + ih];
        #pragma unroll
        for (int kk = 0; kk < 8; kk++)
            *(uint4*)&dstp[kk * 8] = *(const uint4*)&srcp[kk * 8];
    }
}

// Output projection + bias + residual(h) -> tmp (bf16, row-major [M,H])
__global__ __launch_bounds__(256) void gemm_out(
    const bf16* __restrict__ ctx, const bf16* __restrict__ wo,
    const float* __restrict__ bo, const bf16* __restrict__ resid,
    bf16* __restrict__ dst) {
    __shared__ alignas(16) bf16 As[128 * 64];
    __shared__ alignas(16) bf16 Bs[128 * 64];
    int bm = blockIdx.x * 128, bn = blockIdx.y * 128;
    f32x4 acc[4][4];
    for (int mi = 0; mi < 4; mi++)
        for (int ni = 0; ni < 4; ni++)
            for (int r = 0; r < 4; r++) acc[mi][ni][r] = 0.0f;
    gemm128_mainloop(ctx, wo, bm, bn, As, Bs, acc);
    int lane = threadIdx.x & 63, wid = threadIdx.x >> 6;
    int quad = lane >> 4, n = lane & 15;
    int wm = wid & 1, wn = wid >> 1;
    for (int mi = 0; mi < 4; mi++)
        for (int ni = 0; ni < 4; ni++)
            for (int r = 0; r < 4; r++) {
                int i = bm + wm * 64 + mi * 16 + quad * 4 + r;
                int j = bn + wn * 64 + ni * 16 + n;
                float val = acc[mi][ni][r] + bo[j]
                          + (float)resid[(size_t)i * H + j];
                dst[(size_t)i * H + j] = (bf16)val;
            }
}

// ---------------------------------------------------------------------------
// Flash attention v6: split-K x2 (grid.z picks key half; partials additive
// since no online-max), P half-tiles (LDS 36.8KB -> 4 blocks/CU at
// __launch_bounds__(256,4)), mask*log2e folded in via fma.
// Writes numerator N_z (bf16, ctx layout) and denominator l_z (fp32).
// ---------------------------------------------------------------------------
constexpr int LDK2 = 72;    // K tile row stride (64 + 8 pad)
constexpr int LDPH = 72;    // P half-tile row stride (64 + 8 pad)
constexpr int SK   = S / 2; // keys per split

__global__ __launch_bounds__(256, 4) void attn_kernel(
    const bf16* __restrict__ q, const bf16* __restrict__ k,
    const bf16* __restrict__ vt, const float* __restrict__ mask,
    bf16* __restrict__ n0, bf16* __restrict__ n1, float* __restrict__ lp) {
    int bh = blockIdx.y;                 // b*NH + nh
    int b = bh >> 3, nh = bh & 7;
    int z = blockIdx.z;
    int t = threadIdx.x, wid = t >> 6, lane = t & 63;
    int quad = lane >> 4, n = lane & 15;
    int qbase = blockIdx.x * 128 + wid * 32;

    const bf16* Qp = q  + (size_t)bh * S * DH;
    const bf16* Kp = k  + (size_t)bh * S * DH + (size_t)z * SK * DH;
    const bf16* Vt = vt + (size_t)bh * DH * S + (size_t)z * SK;
    const float* mrow = mask + (size_t)b * S + z * SK;
    bf16* Np = (z == 0) ? n0 : n1;

    __shared__ alignas(16) bf16 Ks[128 * LDK2];   // [key][d]
    __shared__ alignas(16) bf16 Ps[4][32 * LDPH]; // per-wave P^T half-tile
    bf16* Pw = Ps[wid];

    bf16x8 qf[2][2];
    #pragma unroll
    for (int qt = 0; qt < 2; qt++)
        #pragma unroll
        for (int hh = 0; hh < 2; hh++)
            qf[qt][hh] = *(const bf16x8*)
                &Qp[(size_t)(qbase + qt * 16 + n) * DH + hh * 32 + quad * 8];

    f32x4 O[2][4];
    #pragma unroll
    for (int qt = 0; qt < 2; qt++)
        for (int i = 0; i < 4; i++)
            for (int r = 0; r < 4; r++) O[qt][i][r] = 0.0f;
    float l_run[2] = {0.0f, 0.0f};

    for (int kb = 0; kb < SK; kb += 128) {
        __syncthreads();
        #pragma unroll
        for (int i = 0; i < 4; i++) {    // stage K 128x64 (16 KB)
            int c = t + i * 256, row = c >> 3, part = c & 7;
            *(uint4*)&Ks[row * LDK2 + part * 8] =
                *(const uint4*)&Kp[(size_t)(kb + row) * DH + part * 8];
        }
        __syncthreads();

        #pragma unroll
        for (int half = 0; half < 2; half++) {
            // V frags for this half's 2 PV k-steps, direct from global.
            bf16x8 vfr[2][4];
            #pragma unroll
            for (int ks = 0; ks < 2; ks++)
                #pragma unroll
                for (int dt = 0; dt < 4; dt++)
                    vfr[ks][dt] = *(const bf16x8*)
                        &Vt[(size_t)(dt * 16 + n) * S + kb + (half * 2 + ks) * 32 + quad * 8];

            #pragma unroll
            for (int kt4 = 0; kt4 < 4; kt4++) {
                int kt = half * 4 + kt4;
                const bf16* kr = &Ks[(kt * 16 + n) * LDK2];
                bf16x8 ka = *(const bf16x8*)&kr[quad * 8];
                bf16x8 kc = *(const bf16x8*)&kr[32 + quad * 8];
                float4 mk = *(const float4*)&mrow[kb + kt * 16 + quad * 4];
                #pragma unroll
                for (int qt = 0; qt < 2; qt++) {
                    f32x4 s;
                    for (int r = 0; r < 4; r++) s[r] = 0.0f;
                    s = __builtin_amdgcn_mfma_f32_16x16x32_bf16(ka, qf[qt][0], s, 0, 0, 0);
                    s = __builtin_amdgcn_mfma_f32_16x16x32_bf16(kc, qf[qt][1], s, 0, 0, 0);
                    float p0 = EXP2(fmaf(mk.x, LOG2E, s[0]));
                    float p1 = EXP2(fmaf(mk.y, LOG2E, s[1]));
                    float p2 = EXP2(fmaf(mk.z, LOG2E, s[2]));
                    float p3 = EXP2(fmaf(mk.w, LOG2E, s[3]));
                    l_run[qt] += (p0 + p1) + (p2 + p3);
                    bf16x4 w;
                    w[0] = (bf16)p0; w[1] = (bf16)p1; w[2] = (bf16)p2; w[3] = (bf16)p3;
                    *(bf16x4*)&Pw[(qt * 16 + n) * LDPH + kt4 * 16 + quad * 4] = w;
                }
            }
            #pragma unroll
            for (int ks = 0; ks < 2; ks++)
                #pragma unroll
                for (int qt = 0; qt < 2; qt++) {
                    bf16x8 pf = *(const bf16x8*)
                        &Pw[(qt * 16 + n) * LDPH + ks * 32 + quad * 8];
                    #pragma unroll
                    for (int dt = 0; dt < 4; dt++)
                        O[qt][dt] = __builtin_amdgcn_mfma_f32_16x16x32_bf16(
                            vfr[ks][dt], pf, O[qt][dt], 0, 0, 0);
                }
        }
    }

    #pragma unroll
    for (int qt = 0; qt < 2; qt++) {
        float l = l_run[qt];
        l += __shfl_xor(l, 16, 64);
        l += __shfl_xor(l, 32, 64);
        int srow = qbase + qt * 16 + n;
        if (quad == 0)
            lp[z * (Bsz * NH * S) + bh * S + srow] = l;
        #pragma unroll
        for (int dt = 0; dt < 4; dt++) {
            bf16x4 o4;
            for (int r = 0; r < 4; r++) o4[r] = (bf16)O[qt][dt][r];
            int col = nh * 64 + dt * 16 + quad * 4;
            *(bf16x4*)&Np[((size_t)(b * S + srow)) * H + col] = o4;
        }
    }
}

// combine: ctx = (N0+N1)/(l0+l1). In-place over n0 is safe (elementwise).
__global__ __launch_bounds__(256) void attn_combine(
    const bf16* __restrict__ N0, const bf16* __restrict__ N1,
    const float* __restrict__ lp, bf16* __restrict__ ctx) {
    int i = (blockIdx.x * 256 + threadIdx.x) * 8;
    int row = i >> 9;                     // / H
    int col = i & (H - 1);
    int b = row >> 11, s = row & (S - 1), nh = col >> 6;
    int lidx = (b * NH + nh) * S + s;
    float li = 1.0f / (lp[lidx] + lp[Bsz * NH * S + lidx]);
    bf16x8 a = *(const bf16x8*)&N0[i];
    bf16x8 c = *(const bf16x8*)&N1[i];
    bf16x8 o;
    #pragma unroll
    for (int r = 0; r < 8; r++) o[r] = (bf16)(((float)a[r] + (float)c[r]) * li);
    *(bf16x8*)&ctx[i] = o;
}

// ---------------------------------------------------------------------------
extern "C" void kernel_launch(void* const* d_in, const int* in_sizes, int n_in,
                              void* d_out, int out_size, void* d_ws, size_t ws_size,
                              hipStream_t stream) {
    const float* hidden = (const float*)d_in[0];
    const float* mask   = (const float*)d_in[1];
    const float* ln1_g  = (const float*)d_in[2];
    const float* ln1_b  = (const float*)d_in[3];
    const float* wq = (const float*)d_in[4],  *bq = (const float*)d_in[5];
    const float* wk = (const float*)d_in[6],  *bk = (const float*)d_in[7];
    const float* wv = (const float*)d_in[8],  *bv = (const float*)d_in[9];
    const float* wo = (const float*)d_in[10], *bo = (const float*)d_in[11];
    const float* ln2_g = (const float*)d_in[12];
    const float* ln2_b = (const float*)d_in[13];

    const size_t T = (size_t)M * H;     // 4M elems per activation tensor
    bf16* wb  = (bf16*)d_ws;            // 4 weights, bf16
    bf16* h   = wb  + (size_t)4 * WELEM;
    bf16* qd  = h   + T;
    bf16* kd  = qd  + T;
    bf16* vtd = kd  + T;
    bf16* N0  = vtd + T;                // numerator z=0; becomes ctx
    bf16* N1  = N0  + T;
    float* lp = (float*)(N1 + T);       // [2][B*NH][S] fp32
    bf16* ctx = N0;
    bf16* tmp = qd;                     // qd dead after attn

    convert_w<<<dim3(WELEM / 1024, 4), 256, 0, stream>>>(wq, wk, wv, wo, wb);
    ln_f32_bf16<<<M / 4, 256, 0, stream>>>(hidden, ln1_g, ln1_b, h);
    gemm_qkv<<<dim3(M / 128, H / 128, 3), 256, 0, stream>>>(
        h, wb, bq, bk, bv, qd, kd, vtd);
    attn_kernel<<<dim3(S / 128, Bsz * NH, 2), 256, 0, stream>>>(
        qd, kd, vtd, mask, N0, N1, lp);
    attn_combine<<<(int)(T / 2048), 256, 0, stream>>>(N0, N1, lp, ctx);
    gemm_out<<<dim3(M / 128, H / 128), 256, 0, stream>>>(
        ctx, wb + (size_t)3 * WELEM, bo, h, tmp);
    ln_bf16_f32<<<M / 4, 256, 0, stream>>>(tmp, ln2_g, ln2_b, (float*)d_out);
}